// Round 1
// baseline (392.941 us; speedup 1.0000x reference)
//
#include <hip/hip_runtime.h>
#include <hip/hip_bf16.h>

typedef __attribute__((ext_vector_type(8))) short short8;
typedef __attribute__((ext_vector_type(4))) float f32x4;

#define DIMC 768
#define HIDDENC 3072
#define NTOK 8192
#define SEQ 1024
#define NHEAD 12
#define HDIM 64

__device__ inline unsigned short f2bf(float f) {
  union { float f; unsigned u; } x; x.f = f;
  unsigned r = (x.u + 0x7FFFu + ((x.u >> 16) & 1u)) >> 16;
  return (unsigned short)r;
}

__device__ inline void gload_lds16(const void* g, void* lds) {
  __builtin_amdgcn_global_load_lds((const __attribute__((address_space(1))) unsigned*)g,
                                   (__attribute__((address_space(3))) unsigned*)lds, 16, 0, 0);
}

// ---------------- weight transpose + fp32->bf16 ----------------
// W: [K][N] f32  ->  Wt: [N][K] bf16
__global__ void wtrans(const float* __restrict__ W, unsigned short* __restrict__ Wt,
                       int K, int N) {
  __shared__ float tile[32][33];
  const int bx = blockIdx.x * 32;  // N
  const int by = blockIdx.y * 32;  // K
  const int tx = threadIdx.x, ty = threadIdx.y;
#pragma unroll
  for (int i = 0; i < 32; i += 8) tile[ty + i][tx] = W[(size_t)(by + ty + i) * N + bx + tx];
  __syncthreads();
#pragma unroll
  for (int i = 0; i < 32; i += 8)
    Wt[(size_t)(bx + ty + i) * K + by + tx] = f2bf(tile[tx][ty + i]);
}

// ---------------- LayerNorm over 768, f32 in -> bf16 out ----------------
__global__ __launch_bounds__(256) void ln_768(const float* __restrict__ x,
                                              const float* __restrict__ g,
                                              const float* __restrict__ b,
                                              unsigned short* __restrict__ out) {
  const int row = blockIdx.x;
  const int t = threadIdx.x;
  const float* xr = x + (size_t)row * DIMC;
  float v0 = xr[t], v1 = xr[t + 256], v2 = xr[t + 512];
  float s = v0 + v1 + v2;
  float ss = v0 * v0 + v1 * v1 + v2 * v2;
#pragma unroll
  for (int m = 1; m < 64; m <<= 1) { s += __shfl_xor(s, m); ss += __shfl_xor(ss, m); }
  __shared__ float red[8];
  const int w = t >> 6, l = t & 63;
  if (l == 0) { red[w] = s; red[4 + w] = ss; }
  __syncthreads();
  s = red[0] + red[1] + red[2] + red[3];
  ss = red[4] + red[5] + red[6] + red[7];
  const float mu = s * (1.0f / 768.0f);
  const float var = ss * (1.0f / 768.0f) - mu * mu;
  const float rstd = rsqrtf(var + 1e-5f);
  out[(size_t)row * DIMC + t]       = f2bf((v0 - mu) * rstd * g[t]       + b[t]);
  out[(size_t)row * DIMC + t + 256] = f2bf((v1 - mu) * rstd * g[t + 256] + b[t + 256]);
  out[(size_t)row * DIMC + t + 512] = f2bf((v2 - mu) * rstd * g[t + 512] + b[t + 512]);
}

// ---------------- GEMM: C[M][N] = A[M][K] @ Bt[N][K]^T + bias (+res) (+gelu) ----------------
// 128x128 tile, BK=32, 4 waves (2x2), each wave 64x64 via 4x4 16x16x32 MFMA frags.
template <int GELU, int RES, int OUT_BF16>
__global__ __launch_bounds__(256) void gemm_bt(const unsigned short* __restrict__ A,
                                               const unsigned short* __restrict__ Bt,
                                               const float* __restrict__ bias,
                                               const float* __restrict__ res,
                                               float* __restrict__ Cf,
                                               unsigned short* __restrict__ Cb,
                                               int M, int N, int K) {
  __shared__ __align__(16) unsigned short As[128 * 32];
  __shared__ __align__(16) unsigned short Bs[128 * 32];
  const int t = threadIdx.x;
  const int w = t >> 6, l = t & 63;
  const int lr = l & 15, lg = l >> 4;
  const int wr = w >> 1, wc = w & 1;
  const unsigned short* Ag = A + (size_t)blockIdx.y * 128 * K;
  const unsigned short* Bg = Bt + (size_t)blockIdx.x * 128 * K;
  const int c1 = t, c2 = t + 256;
  const size_t a1 = (size_t)(c1 >> 2) * K + (size_t)(c1 & 3) * 8;
  const size_t a2 = (size_t)(c2 >> 2) * K + (size_t)(c2 & 3) * 8;
  f32x4 acc[4][4] = {};
  for (int k0 = 0; k0 < K; k0 += 32) {
    gload_lds16(Ag + a1 + k0, &As[w * 512]);
    gload_lds16(Ag + a2 + k0, &As[2048 + w * 512]);
    gload_lds16(Bg + a1 + k0, &Bs[w * 512]);
    gload_lds16(Bg + a2 + k0, &Bs[2048 + w * 512]);
    __syncthreads();
    short8 af[4], bf[4];
#pragma unroll
    for (int i = 0; i < 4; i++) af[i] = *(const short8*)&As[(wr * 64 + i * 16 + lr) * 32 + lg * 8];
#pragma unroll
    for (int i = 0; i < 4; i++) bf[i] = *(const short8*)&Bs[(wc * 64 + i * 16 + lr) * 32 + lg * 8];
#pragma unroll
    for (int i = 0; i < 4; i++)
#pragma unroll
      for (int j = 0; j < 4; j++)
        acc[i][j] = __builtin_amdgcn_mfma_f32_16x16x32_bf16(af[i], bf[j], acc[i][j], 0, 0, 0);
    __syncthreads();
  }
  const int rbase = blockIdx.y * 128 + wr * 64;
  const int cbase = blockIdx.x * 128 + wc * 64;
#pragma unroll
  for (int i = 0; i < 4; i++)
#pragma unroll
    for (int j = 0; j < 4; j++) {
      const int c = cbase + j * 16 + lr;
      const float bz = bias[c];
#pragma unroll
      for (int v = 0; v < 4; v++) {
        const int r = rbase + i * 16 + lg * 4 + v;
        float val = acc[i][j][v] + bz;
        if (RES) val += res[(size_t)r * N + c];
        if (GELU) val = 0.5f * val * (1.0f + erff(val * 0.70710678118654752f));
        if (OUT_BF16) Cb[(size_t)r * N + c] = f2bf(val);
        else          Cf[(size_t)r * N + c] = val;
      }
    }
}

// ---------------- fused attention ----------------
// qkv bf16 [8192][2304] (cols: [3][12][64]); o bf16 [8192][768]
// grid (16 qtiles, 12 heads, 8 batch), 256 threads (4 waves, 16 q-rows each)
__global__ __launch_bounds__(256) void attn(const unsigned short* __restrict__ qkv,
                                            unsigned short* __restrict__ o) {
  const int qt = blockIdx.x, h = blockIdx.y, b = blockIdx.z;
  const int t = threadIdx.x, w = t >> 6, l = t & 63;
  const int lr = l & 15, lg = l >> 4;
  const int ld = 3 * DIMC;
  __shared__ __align__(16) unsigned short Ks[64 * 64];   // [k][d]
  __shared__ __align__(16) unsigned short Vt[64 * 64];   // [d][k]
  __shared__ __align__(16) unsigned short Ps[4][16 * 64]; // per-wave [q][k]

  const unsigned short* qb = qkv + (size_t)(b * SEQ + qt * 64 + w * 16) * ld + h * HDIM;
  short8 qf0 = *(const short8*)(qb + (size_t)lr * ld + lg * 8);
  short8 qf1 = *(const short8*)(qb + (size_t)lr * ld + 32 + lg * 8);

  float m_run[4], l_run[4];
  f32x4 oacc[4];
#pragma unroll
  for (int v = 0; v < 4; v++) { m_run[v] = -1e30f; l_run[v] = 0.f; }
#pragma unroll
  for (int i = 0; i < 4; i++) oacc[i] = (f32x4){0.f, 0.f, 0.f, 0.f};

  for (int kt = 0; kt < 16; ++kt) {
    const unsigned short* kb = qkv + (size_t)(b * SEQ + kt * 64) * ld + DIMC + h * HDIM;
    const unsigned short* vb = kb + DIMC;
    {
      const int r = t >> 2, c4 = (t & 3) * 16;
      *(short8*)&Ks[r * 64 + c4]     = *(const short8*)(kb + (size_t)r * ld + c4);
      *(short8*)&Ks[r * 64 + c4 + 8] = *(const short8*)(kb + (size_t)r * ld + c4 + 8);
      __align__(16) unsigned short tmp[16];
      *(short8*)&tmp[0] = *(const short8*)(vb + (size_t)r * ld + c4);
      *(short8*)&tmp[8] = *(const short8*)(vb + (size_t)r * ld + c4 + 8);
#pragma unroll
      for (int i = 0; i < 16; i++) Vt[(c4 + i) * 64 + r] = tmp[i];
    }
    __syncthreads();

    f32x4 sf[4];
#pragma unroll
    for (int n = 0; n < 4; n++) sf[n] = (f32x4){0.f, 0.f, 0.f, 0.f};
#pragma unroll
    for (int kc = 0; kc < 2; kc++) {
      short8 q = kc ? qf1 : qf0;
#pragma unroll
      for (int n = 0; n < 4; n++) {
        short8 kf = *(const short8*)&Ks[(n * 16 + lr) * 64 + kc * 32 + lg * 8];
        sf[n] = __builtin_amdgcn_mfma_f32_16x16x32_bf16(q, kf, sf[n], 0, 0, 0);
      }
    }

    // scale + clamp + online softmax. lane holds S[q=lg*4+v][k=n*16+lr]
    float pv[4][4];
    float rmax[4];
#pragma unroll
    for (int v = 0; v < 4; v++) rmax[v] = -1e30f;
#pragma unroll
    for (int n = 0; n < 4; n++)
#pragma unroll
      for (int v = 0; v < 4; v++) {
        float s = sf[n][v] * 0.125f;
        s = fminf(fmaxf(s, -50.f), 50.f);
        pv[n][v] = s;
        rmax[v] = fmaxf(rmax[v], s);
      }
#pragma unroll
    for (int m = 1; m < 16; m <<= 1)
#pragma unroll
      for (int v = 0; v < 4; v++) rmax[v] = fmaxf(rmax[v], __shfl_xor(rmax[v], m));
    float psum[4];
#pragma unroll
    for (int v = 0; v < 4; v++) {
      float mn = fmaxf(m_run[v], rmax[v]);
      float alpha = __expf(m_run[v] - mn);
      m_run[v] = mn;
      l_run[v] *= alpha;
#pragma unroll
      for (int dn = 0; dn < 4; dn++) oacc[dn][v] *= alpha;
      psum[v] = 0.f;
    }
#pragma unroll
    for (int n = 0; n < 4; n++)
#pragma unroll
      for (int v = 0; v < 4; v++) {
        float e = __expf(pv[n][v] - m_run[v]);
        psum[v] += e;
        Ps[w][(lg * 4 + v) * 64 + n * 16 + lr] = f2bf(e);
      }
#pragma unroll
    for (int m = 1; m < 16; m <<= 1)
#pragma unroll
      for (int v = 0; v < 4; v++) psum[v] += __shfl_xor(psum[v], m);
#pragma unroll
    for (int v = 0; v < 4; v++) l_run[v] += psum[v];
    __syncthreads();

    // PV: A = P [q=lr][k], B = Vt [d=dn*16+lr][k]
#pragma unroll
    for (int kc = 0; kc < 2; kc++) {
      short8 pf = *(const short8*)&Ps[w][lr * 64 + kc * 32 + lg * 8];
#pragma unroll
      for (int dn = 0; dn < 4; dn++) {
        short8 vf = *(const short8*)&Vt[(dn * 16 + lr) * 64 + kc * 32 + lg * 8];
        oacc[dn] = __builtin_amdgcn_mfma_f32_16x16x32_bf16(pf, vf, oacc[dn], 0, 0, 0);
      }
    }
    __syncthreads();
  }

  unsigned short* ob = o + (size_t)(b * SEQ + qt * 64 + w * 16) * DIMC + h * HDIM;
#pragma unroll
  for (int v = 0; v < 4; v++) {
    const float inv = 1.0f / l_run[v];
#pragma unroll
    for (int dn = 0; dn < 4; dn++)
      ob[(size_t)(lg * 4 + v) * DIMC + dn * 16 + lr] = f2bf(oacc[dn][v] * inv);
  }
}

extern "C" void kernel_launch(void* const* d_in, const int* in_sizes, int n_in,
                              void* d_out, int out_size, void* d_ws, size_t ws_size,
                              hipStream_t stream) {
  const float* x      = (const float*)d_in[0];
  const float* ln1_g  = (const float*)d_in[1];
  const float* ln1_b  = (const float*)d_in[2];
  const float* w_qkv  = (const float*)d_in[3];
  const float* b_qkv  = (const float*)d_in[4];
  const float* w_proj = (const float*)d_in[5];
  const float* b_proj = (const float*)d_in[6];
  const float* ln2_g  = (const float*)d_in[7];
  const float* ln2_b  = (const float*)d_in[8];
  const float* w_fc1  = (const float*)d_in[9];
  const float* b_fc1  = (const float*)d_in[10];
  const float* w_fc2  = (const float*)d_in[11];
  const float* b_fc2  = (const float*)d_in[12];
  float* out = (float*)d_out;

  char* p = (char*)d_ws;
  unsigned short* wqkvT  = (unsigned short*)p; p += (size_t)2304 * 768 * 2;
  unsigned short* wprojT = (unsigned short*)p; p += (size_t)768 * 768 * 2;
  unsigned short* wfc1T  = (unsigned short*)p; p += (size_t)3072 * 768 * 2;
  unsigned short* wfc2T  = (unsigned short*)p; p += (size_t)768 * 3072 * 2;
  unsigned short* h1     = (unsigned short*)p; p += (size_t)NTOK * 768 * 2;   // also h2
  float*          x1     = (float*)p;          p += (size_t)NTOK * 768 * 4;
  unsigned short* qkv    = (unsigned short*)p; p += (size_t)NTOK * 2304 * 2;
  unsigned short* ob     = (unsigned short*)p; p += (size_t)NTOK * 768 * 2;
  unsigned short* g      = qkv;  // alias: qkv+o region (exactly 8192*3072*2 bytes), dead by FC1

  dim3 tb(32, 8);
  wtrans<<<dim3(2304 / 32, 768 / 32), tb, 0, stream>>>(w_qkv, wqkvT, 768, 2304);
  wtrans<<<dim3(768 / 32, 768 / 32), tb, 0, stream>>>(w_proj, wprojT, 768, 768);
  wtrans<<<dim3(3072 / 32, 768 / 32), tb, 0, stream>>>(w_fc1, wfc1T, 768, 3072);
  wtrans<<<dim3(768 / 32, 3072 / 32), tb, 0, stream>>>(w_fc2, wfc2T, 3072, 768);

  ln_768<<<NTOK, 256, 0, stream>>>(x, ln1_g, ln1_b, h1);
  gemm_bt<0, 0, 1><<<dim3(18, 64), 256, 0, stream>>>(h1, wqkvT, b_qkv, nullptr, nullptr, qkv,
                                                     NTOK, 2304, 768);
  attn<<<dim3(16, 12, 8), 256, 0, stream>>>(qkv, ob);
  gemm_bt<0, 1, 0><<<dim3(6, 64), 256, 0, stream>>>(ob, wprojT, b_proj, x, x1, nullptr,
                                                    NTOK, 768, 768);
  ln_768<<<NTOK, 256, 0, stream>>>(x1, ln2_g, ln2_b, h1);
  gemm_bt<1, 0, 1><<<dim3(24, 64), 256, 0, stream>>>(h1, wfc1T, b_fc1, nullptr, nullptr, g,
                                                     NTOK, 3072, 768);
  gemm_bt<0, 1, 0><<<dim3(6, 64), 256, 0, stream>>>(g, wfc2T, b_fc2, x1, out, nullptr,
                                                    NTOK, 768, 3072);
}

// Round 5
// 353.805 us; speedup vs baseline: 1.1106x; 1.1106x over previous
//
#include <hip/hip_runtime.h>
#include <hip/hip_bf16.h>

typedef __attribute__((ext_vector_type(8))) short short8;
typedef __attribute__((ext_vector_type(4))) float f32x4;

#define DIMC 768
#define HIDDENC 3072
#define NTOK 8192
#define SEQ 1024
#define NHEAD 12
#define HDIM 64

__device__ inline unsigned short f2bf(float f) {
  union { float f; unsigned u; } x; x.f = f;
  unsigned r = (x.u + 0x7FFFu + ((x.u >> 16) & 1u)) >> 16;
  return (unsigned short)r;
}

__device__ inline void gload_lds16(const void* g, void* lds) {
  __builtin_amdgcn_global_load_lds((const __attribute__((address_space(1))) unsigned*)g,
                                   (__attribute__((address_space(3))) unsigned*)lds, 16, 0, 0);
}

// ---------------- weight transpose + fp32->bf16 ----------------
// W: [K][N] f32  ->  Wt: [N][K] bf16
__global__ void wtrans(const float* __restrict__ W, unsigned short* __restrict__ Wt,
                       int K, int N) {
  __shared__ float tile[32][33];
  const int bx = blockIdx.x * 32;  // N
  const int by = blockIdx.y * 32;  // K
  const int tx = threadIdx.x, ty = threadIdx.y;
#pragma unroll
  for (int i = 0; i < 32; i += 8) tile[ty + i][tx] = W[(size_t)(by + ty + i) * N + bx + tx];
  __syncthreads();
#pragma unroll
  for (int i = 0; i < 32; i += 8)
    Wt[(size_t)(bx + ty + i) * K + by + tx] = f2bf(tile[tx][ty + i]);
}

// ---------------- V transpose: qkv V-part -> vT[b*768 + (h*64+d)][n] ----------------
__global__ void vtrans(const unsigned short* __restrict__ qkv, unsigned short* __restrict__ vT) {
  __shared__ unsigned short tile[32][33];
  const int bc = blockIdx.x * 32;  // c in [0,768)
  const int bn = blockIdx.y * 32;  // n in [0,1024)
  const int b = blockIdx.z;
  const int tx = threadIdx.x, ty = threadIdx.y;
#pragma unroll
  for (int i = 0; i < 32; i += 8)
    tile[ty + i][tx] = qkv[(size_t)(b * SEQ + bn + ty + i) * (3 * DIMC) + 2 * DIMC + bc + tx];
  __syncthreads();
#pragma unroll
  for (int i = 0; i < 32; i += 8)
    vT[(size_t)(b * DIMC + bc + ty + i) * SEQ + bn + tx] = tile[tx][ty + i];
}

// ---------------- LayerNorm over 768, f32 in -> bf16 out ----------------
__global__ __launch_bounds__(256) void ln_768(const float* __restrict__ x,
                                              const float* __restrict__ g,
                                              const float* __restrict__ b,
                                              unsigned short* __restrict__ out) {
  const int row = blockIdx.x;
  const int t = threadIdx.x;
  const float* xr = x + (size_t)row * DIMC;
  float v0 = xr[t], v1 = xr[t + 256], v2 = xr[t + 512];
  float s = v0 + v1 + v2;
  float ss = v0 * v0 + v1 * v1 + v2 * v2;
#pragma unroll
  for (int m = 1; m < 64; m <<= 1) { s += __shfl_xor(s, m); ss += __shfl_xor(ss, m); }
  __shared__ float red[8];
  const int w = t >> 6, l = t & 63;
  if (l == 0) { red[w] = s; red[4 + w] = ss; }
  __syncthreads();
  s = red[0] + red[1] + red[2] + red[3];
  ss = red[4] + red[5] + red[6] + red[7];
  const float mu = s * (1.0f / 768.0f);
  const float var = ss * (1.0f / 768.0f) - mu * mu;
  const float rstd = rsqrtf(var + 1e-5f);
  out[(size_t)row * DIMC + t]       = f2bf((v0 - mu) * rstd * g[t]       + b[t]);
  out[(size_t)row * DIMC + t + 256] = f2bf((v1 - mu) * rstd * g[t + 256] + b[t + 256]);
  out[(size_t)row * DIMC + t + 512] = f2bf((v2 - mu) * rstd * g[t + 512] + b[t + 512]);
}

// ---------------- GEMM: C[M][N] = A[M][K] @ Bt[N][K]^T + bias (+res) (+gelu) ----------------
// 128x128 tile, BK=32, 4 waves (2x2), each wave 64x64 via 4x4 16x16x32 MFMA frags.
template <int GELU, int RES, int OUT_BF16>
__global__ __launch_bounds__(256) void gemm_bt(const unsigned short* __restrict__ A,
                                               const unsigned short* __restrict__ Bt,
                                               const float* __restrict__ bias,
                                               const float* __restrict__ res,
                                               float* __restrict__ Cf,
                                               unsigned short* __restrict__ Cb,
                                               int M, int N, int K) {
  __shared__ __align__(16) unsigned short As[128 * 32];
  __shared__ __align__(16) unsigned short Bs[128 * 32];
  const int t = threadIdx.x;
  const int w = t >> 6, l = t & 63;
  const int lr = l & 15, lg = l >> 4;
  const int wr = w >> 1, wc = w & 1;
  const unsigned short* Ag = A + (size_t)blockIdx.y * 128 * K;
  const unsigned short* Bg = Bt + (size_t)blockIdx.x * 128 * K;
  const int c1 = t, c2 = t + 256;
  const size_t a1 = (size_t)(c1 >> 2) * K + (size_t)(c1 & 3) * 8;
  const size_t a2 = (size_t)(c2 >> 2) * K + (size_t)(c2 & 3) * 8;
  f32x4 acc[4][4] = {};
  for (int k0 = 0; k0 < K; k0 += 32) {
    gload_lds16(Ag + a1 + k0, &As[w * 512]);
    gload_lds16(Ag + a2 + k0, &As[2048 + w * 512]);
    gload_lds16(Bg + a1 + k0, &Bs[w * 512]);
    gload_lds16(Bg + a2 + k0, &Bs[2048 + w * 512]);
    __syncthreads();
    short8 af[4], bf[4];
#pragma unroll
    for (int i = 0; i < 4; i++) af[i] = *(const short8*)&As[(wr * 64 + i * 16 + lr) * 32 + lg * 8];
#pragma unroll
    for (int i = 0; i < 4; i++) bf[i] = *(const short8*)&Bs[(wc * 64 + i * 16 + lr) * 32 + lg * 8];
#pragma unroll
    for (int i = 0; i < 4; i++)
#pragma unroll
      for (int j = 0; j < 4; j++)
        acc[i][j] = __builtin_amdgcn_mfma_f32_16x16x32_bf16(af[i], bf[j], acc[i][j], 0, 0, 0);
    __syncthreads();
  }
  const int rbase = blockIdx.y * 128 + wr * 64;
  const int cbase = blockIdx.x * 128 + wc * 64;
#pragma unroll
  for (int i = 0; i < 4; i++)
#pragma unroll
    for (int j = 0; j < 4; j++) {
      const int c = cbase + j * 16 + lr;
      const float bz = bias[c];
#pragma unroll
      for (int v = 0; v < 4; v++) {
        const int r = rbase + i * 16 + lg * 4 + v;
        float val = acc[i][j][v] + bz;
        if (RES) val += res[(size_t)r * N + c];
        if (GELU) val = 0.5f * val * (1.0f + erff(val * 0.70710678118654752f));
        if (OUT_BF16) Cb[(size_t)r * N + c] = f2bf(val);
        else          Cf[(size_t)r * N + c] = val;
      }
    }
}

// ---------------- fused attention (v3: round-1 dataflow + XOR-swizzled LDS, pre-transposed V) ----
// qkv bf16 [8192][2304]; vT bf16 [8*768][1024]; o bf16 [8192][768]
// grid (16 qtiles, 12 heads, 8 batch), 256 threads (4 waves, 16 q-rows each)
// All LDS tiles are [row][64] with byte-XOR swizzle: byte_in_row ^= (row&7)<<4.
__global__ __launch_bounds__(256) void attn(const unsigned short* __restrict__ qkv,
                                            const unsigned short* __restrict__ vT,
                                            unsigned short* __restrict__ o) {
  const int qt = blockIdx.x, h = blockIdx.y, b = blockIdx.z;
  const int t = threadIdx.x, w = t >> 6, l = t & 63;
  const int lr = l & 15, lg = l >> 4;
  const int ld = 3 * DIMC;
  __shared__ __align__(16) unsigned short Ks[64 * 64];
  __shared__ __align__(16) unsigned short Vt[64 * 64];
  __shared__ __align__(16) unsigned short Ps[4][16 * 64];

  const unsigned short* qb = qkv + (size_t)(b * SEQ + qt * 64 + w * 16) * ld + h * HDIM;
  short8 qf0 = *(const short8*)(qb + (size_t)lr * ld + lg * 8);
  short8 qf1 = *(const short8*)(qb + (size_t)lr * ld + 32 + lg * 8);

  // per-thread V^T staging source: row d = t>>2 of this (b,h) head, cols = seq
  const unsigned short* vrow = vT + (size_t)(b * DIMC + h * HDIM + (t >> 2)) * SEQ;

  float m_run[4], l_run[4];
  f32x4 oacc[4];
#pragma unroll
  for (int v = 0; v < 4; v++) { m_run[v] = -1e30f; l_run[v] = 0.f; }
#pragma unroll
  for (int i = 0; i < 4; i++) oacc[i] = (f32x4){0.f, 0.f, 0.f, 0.f};

  for (int kt = 0; kt < 16; ++kt) {
    const unsigned short* kb = qkv + (size_t)(b * SEQ + kt * 64) * ld + DIMC + h * HDIM;
    {
      const int r = t >> 2, c4 = (t & 3) * 16;
      const int sw = (r & 7) << 4;
      short8 kv0 = *(const short8*)(kb + (size_t)r * ld + c4);
      short8 kv1 = *(const short8*)(kb + (size_t)r * ld + c4 + 8);
      char* ksb = (char*)Ks + r * 128;
      *(short8*)(ksb + ((c4 * 2) ^ sw))      = kv0;
      *(short8*)(ksb + ((c4 * 2 + 16) ^ sw)) = kv1;
      short8 tv0 = *(const short8*)(vrow + kt * 64 + c4);
      short8 tv1 = *(const short8*)(vrow + kt * 64 + c4 + 8);
      char* vsb = (char*)Vt + r * 128;
      *(short8*)(vsb + ((c4 * 2) ^ sw))      = tv0;
      *(short8*)(vsb + ((c4 * 2 + 16) ^ sw)) = tv1;
    }
    __syncthreads();

    // ---- QK^T : S[q][k], A=Q rows, B=K rows (swizzled reads) ----
    f32x4 sf[4];
#pragma unroll
    for (int n = 0; n < 4; n++) sf[n] = (f32x4){0.f, 0.f, 0.f, 0.f};
#pragma unroll
    for (int kc = 0; kc < 2; kc++) {
      short8 q = kc ? qf1 : qf0;
#pragma unroll
      for (int n = 0; n < 4; n++) {
        const int row = n * 16 + lr;
        short8 kf = *(const short8*)((const char*)Ks + row * 128 +
                                     (((kc * 32 + lg * 8) * 2) ^ ((row & 7) << 4)));
        sf[n] = __builtin_amdgcn_mfma_f32_16x16x32_bf16(q, kf, sf[n], 0, 0, 0);
      }
    }

    // ---- online softmax; lane holds S[q=lg*4+v][k=n*16+lr] ----
    float pv[4][4];
    float rmax[4];
#pragma unroll
    for (int v = 0; v < 4; v++) rmax[v] = -1e30f;
#pragma unroll
    for (int n = 0; n < 4; n++)
#pragma unroll
      for (int v = 0; v < 4; v++) {
        float s = sf[n][v] * 0.125f;
        s = fminf(fmaxf(s, -50.f), 50.f);
        pv[n][v] = s;
        rmax[v] = fmaxf(rmax[v], s);
      }
#pragma unroll
    for (int m = 1; m < 16; m <<= 1)
#pragma unroll
      for (int v = 0; v < 4; v++) rmax[v] = fmaxf(rmax[v], __shfl_xor(rmax[v], m));
    float psum[4];
#pragma unroll
    for (int v = 0; v < 4; v++) {
      float mn = fmaxf(m_run[v], rmax[v]);
      float alpha = __expf(m_run[v] - mn);
      m_run[v] = mn;
      l_run[v] *= alpha;
#pragma unroll
      for (int dn = 0; dn < 4; dn++) oacc[dn][v] *= alpha;
      psum[v] = 0.f;
    }
    char* psw = (char*)&Ps[w][0];
#pragma unroll
    for (int n = 0; n < 4; n++)
#pragma unroll
      for (int v = 0; v < 4; v++) {
        float e = __expf(pv[n][v] - m_run[v]);
        psum[v] += e;
        const int q = lg * 4 + v;
        *(unsigned short*)(psw + q * 128 + ((((n * 16 + lr) * 2)) ^ ((q & 7) << 4))) = f2bf(e);
      }
#pragma unroll
    for (int m = 1; m < 16; m <<= 1)
#pragma unroll
      for (int v = 0; v < 4; v++) psum[v] += __shfl_xor(psum[v], m);
#pragma unroll
    for (int v = 0; v < 4; v++) l_run[v] += psum[v];

    // drain wave-local Ps writes before reading them (no block barrier needed)
    asm volatile("s_waitcnt lgkmcnt(0)" ::: "memory");
    __builtin_amdgcn_sched_barrier(0);

    // ---- PV: A = P[q=lr][k-frag], B = Vt[d=dn*16+lr][k-frag] (swizzled reads) ----
#pragma unroll
    for (int kc = 0; kc < 2; kc++) {
      short8 pf = *(const short8*)((const char*)&Ps[w][0] + lr * 128 +
                                   (((kc * 32 + lg * 8) * 2) ^ ((lr & 7) << 4)));
#pragma unroll
      for (int dn = 0; dn < 4; dn++) {
        const int row = dn * 16 + lr;
        short8 vf = *(const short8*)((const char*)Vt + row * 128 +
                                     (((kc * 32 + lg * 8) * 2) ^ ((row & 7) << 4)));
        oacc[dn] = __builtin_amdgcn_mfma_f32_16x16x32_bf16(pf, vf, oacc[dn], 0, 0, 0);
      }
    }
    __syncthreads();
  }

  unsigned short* ob = o + (size_t)(b * SEQ + qt * 64 + w * 16) * DIMC + h * HDIM;
#pragma unroll
  for (int v = 0; v < 4; v++) {
    const float inv = 1.0f / l_run[v];
#pragma unroll
    for (int dn = 0; dn < 4; dn++)
      ob[(size_t)(lg * 4 + v) * DIMC + dn * 16 + lr] = f2bf(oacc[dn][v] * inv);
  }
}

extern "C" void kernel_launch(void* const* d_in, const int* in_sizes, int n_in,
                              void* d_out, int out_size, void* d_ws, size_t ws_size,
                              hipStream_t stream) {
  const float* x      = (const float*)d_in[0];
  const float* ln1_g  = (const float*)d_in[1];
  const float* ln1_b  = (const float*)d_in[2];
  const float* w_qkv  = (const float*)d_in[3];
  const float* b_qkv  = (const float*)d_in[4];
  const float* w_proj = (const float*)d_in[5];
  const float* b_proj = (const float*)d_in[6];
  const float* ln2_g  = (const float*)d_in[7];
  const float* ln2_b  = (const float*)d_in[8];
  const float* w_fc1  = (const float*)d_in[9];
  const float* b_fc1  = (const float*)d_in[10];
  const float* w_fc2  = (const float*)d_in[11];
  const float* b_fc2  = (const float*)d_in[12];
  float* out = (float*)d_out;

  char* p = (char*)d_ws;
  unsigned short* wqkvT  = (unsigned short*)p; p += (size_t)2304 * 768 * 2;
  unsigned short* wprojT = (unsigned short*)p; p += (size_t)768 * 768 * 2;
  unsigned short* wfc1T  = (unsigned short*)p; p += (size_t)3072 * 768 * 2;
  unsigned short* wfc2T  = (unsigned short*)p; p += (size_t)768 * 3072 * 2;
  unsigned short* h1     = (unsigned short*)p; p += (size_t)NTOK * 768 * 2;
  float*          x1     = (float*)p;          p += (size_t)NTOK * 768 * 4;
  unsigned short* qkv    = (unsigned short*)p; p += (size_t)NTOK * 2304 * 2;
  unsigned short* ob     = (unsigned short*)p; p += (size_t)NTOK * 768 * 2;
  unsigned short* g      = qkv;            // alias: qkv region, dead by FC1
  unsigned short* vT     = (unsigned short*)x1;  // alias: x1 dead until proj GEMM; vT dead after attn

  dim3 tb(32, 8);
  wtrans<<<dim3(2304 / 32, 768 / 32), tb, 0, stream>>>(w_qkv, wqkvT, 768, 2304);
  wtrans<<<dim3(768 / 32, 768 / 32), tb, 0, stream>>>(w_proj, wprojT, 768, 768);
  wtrans<<<dim3(3072 / 32, 768 / 32), tb, 0, stream>>>(w_fc1, wfc1T, 768, 3072);
  wtrans<<<dim3(768 / 32, 3072 / 32), tb, 0, stream>>>(w_fc2, wfc2T, 3072, 768);

  ln_768<<<NTOK, 256, 0, stream>>>(x, ln1_g, ln1_b, h1);
  gemm_bt<0, 0, 1><<<dim3(18, 64), 256, 0, stream>>>(h1, wqkvT, b_qkv, nullptr, nullptr, qkv,
                                                     NTOK, 2304, 768);
  vtrans<<<dim3(24, 32, 8), tb, 0, stream>>>(qkv, vT);
  attn<<<dim3(16, 12, 8), 256, 0, stream>>>(qkv, vT, ob);
  gemm_bt<0, 1, 0><<<dim3(6, 64), 256, 0, stream>>>(ob, wprojT, b_proj, x, x1, nullptr,
                                                    NTOK, 768, 768);
  ln_768<<<NTOK, 256, 0, stream>>>(x1, ln2_g, ln2_b, h1);
  gemm_bt<1, 0, 1><<<dim3(24, 64), 256, 0, stream>>>(h1, wfc1T, b_fc1, nullptr, nullptr, g,
                                                     NTOK, 3072, 768);
  gemm_bt<0, 1, 0><<<dim3(6, 64), 256, 0, stream>>>(g, wfc2T, b_fc2, x1, out, nullptr,
                                                    NTOK, 768, 3072);
}

// Round 6
// 320.344 us; speedup vs baseline: 1.2266x; 1.1045x over previous
//
#include <hip/hip_runtime.h>
#include <hip/hip_bf16.h>

typedef __attribute__((ext_vector_type(8))) short short8;
typedef __attribute__((ext_vector_type(4))) float f32x4;
typedef __attribute__((ext_vector_type(4))) unsigned short us4;

#define DIMC 768
#define HIDDENC 3072
#define NTOK 8192
#define SEQ 1024
#define NHEAD 12
#define HDIM 64

__device__ inline unsigned short f2bf(float f) {
  union { float f; unsigned u; } x; x.f = f;
  unsigned r = (x.u + 0x7FFFu + ((x.u >> 16) & 1u)) >> 16;
  return (unsigned short)r;
}

__device__ inline void gload_lds16(const void* g, void* lds) {
  __builtin_amdgcn_global_load_lds((const __attribute__((address_space(1))) unsigned*)g,
                                   (__attribute__((address_space(3))) unsigned*)lds, 16, 0, 0);
}

// ---------------- weight transpose + fp32->bf16 ----------------
// W: [K][N] f32  ->  Wt: [N][K] bf16
__global__ void wtrans(const float* __restrict__ W, unsigned short* __restrict__ Wt,
                       int K, int N) {
  __shared__ float tile[32][33];
  const int bx = blockIdx.x * 32;  // N
  const int by = blockIdx.y * 32;  // K
  const int tx = threadIdx.x, ty = threadIdx.y;
#pragma unroll
  for (int i = 0; i < 32; i += 8) tile[ty + i][tx] = W[(size_t)(by + ty + i) * N + bx + tx];
  __syncthreads();
#pragma unroll
  for (int i = 0; i < 32; i += 8)
    Wt[(size_t)(bx + ty + i) * K + by + tx] = f2bf(tile[tx][ty + i]);
}

// ---------------- V transpose: qkv V-part -> vT[b*768 + (h*64+d)][n] ----------------
__global__ void vtrans(const unsigned short* __restrict__ qkv, unsigned short* __restrict__ vT) {
  __shared__ unsigned short tile[32][33];
  const int bc = blockIdx.x * 32;  // c in [0,768)
  const int bn = blockIdx.y * 32;  // n in [0,1024)
  const int b = blockIdx.z;
  const int tx = threadIdx.x, ty = threadIdx.y;
#pragma unroll
  for (int i = 0; i < 32; i += 8)
    tile[ty + i][tx] = qkv[(size_t)(b * SEQ + bn + ty + i) * (3 * DIMC) + 2 * DIMC + bc + tx];
  __syncthreads();
#pragma unroll
  for (int i = 0; i < 32; i += 8)
    vT[(size_t)(b * DIMC + bc + ty + i) * SEQ + bn + tx] = tile[tx][ty + i];
}

// ---------------- LayerNorm over 768, f32 in -> bf16 out ----------------
__global__ __launch_bounds__(256) void ln_768(const float* __restrict__ x,
                                              const float* __restrict__ g,
                                              const float* __restrict__ b,
                                              unsigned short* __restrict__ out) {
  const int row = blockIdx.x;
  const int t = threadIdx.x;
  const float* xr = x + (size_t)row * DIMC;
  float v0 = xr[t], v1 = xr[t + 256], v2 = xr[t + 512];
  float s = v0 + v1 + v2;
  float ss = v0 * v0 + v1 * v1 + v2 * v2;
#pragma unroll
  for (int m = 1; m < 64; m <<= 1) { s += __shfl_xor(s, m); ss += __shfl_xor(ss, m); }
  __shared__ float red[8];
  const int w = t >> 6, l = t & 63;
  if (l == 0) { red[w] = s; red[4 + w] = ss; }
  __syncthreads();
  s = red[0] + red[1] + red[2] + red[3];
  ss = red[4] + red[5] + red[6] + red[7];
  const float mu = s * (1.0f / 768.0f);
  const float var = ss * (1.0f / 768.0f) - mu * mu;
  const float rstd = rsqrtf(var + 1e-5f);
  out[(size_t)row * DIMC + t]       = f2bf((v0 - mu) * rstd * g[t]       + b[t]);
  out[(size_t)row * DIMC + t + 256] = f2bf((v1 - mu) * rstd * g[t + 256] + b[t + 256]);
  out[(size_t)row * DIMC + t + 512] = f2bf((v2 - mu) * rstd * g[t + 512] + b[t + 512]);
}

// ---------------- GEMM: C[M][N] = A[M][K] @ Bt[N][K]^T + bias (+res) (+gelu) ----------------
// 128x128 tile, BK=32, 4 waves (2x2). XCD-aware block swizzle (T1): grid sizes all %8==0.
template <int GELU, int RES, int OUT_BF16>
__global__ __launch_bounds__(256) void gemm_bt(const unsigned short* __restrict__ A,
                                               const unsigned short* __restrict__ Bt,
                                               const float* __restrict__ bias,
                                               const float* __restrict__ res,
                                               float* __restrict__ Cf,
                                               unsigned short* __restrict__ Cb,
                                               int M, int N, int K) {
  __shared__ __align__(16) unsigned short As[128 * 32];
  __shared__ __align__(16) unsigned short Bs[128 * 32];
  const int gx = gridDim.x;
  const int nwg = gx * gridDim.y;
  const int orig = blockIdx.y * gx + blockIdx.x;
  const int cpx = nwg >> 3;                       // chunk per XCD (nwg % 8 == 0)
  const int wg = (orig & 7) * cpx + (orig >> 3);  // contiguous chunk per XCD
  const int bxx = wg % gx, byy = wg / gx;
  const int t = threadIdx.x;
  const int w = t >> 6, l = t & 63;
  const int lr = l & 15, lg = l >> 4;
  const int wr = w >> 1, wc = w & 1;
  const unsigned short* Ag = A + (size_t)byy * 128 * K;
  const unsigned short* Bg = Bt + (size_t)bxx * 128 * K;
  const int c1 = t, c2 = t + 256;
  const size_t a1 = (size_t)(c1 >> 2) * K + (size_t)(c1 & 3) * 8;
  const size_t a2 = (size_t)(c2 >> 2) * K + (size_t)(c2 & 3) * 8;
  f32x4 acc[4][4] = {};
  for (int k0 = 0; k0 < K; k0 += 32) {
    gload_lds16(Ag + a1 + k0, &As[w * 512]);
    gload_lds16(Ag + a2 + k0, &As[2048 + w * 512]);
    gload_lds16(Bg + a1 + k0, &Bs[w * 512]);
    gload_lds16(Bg + a2 + k0, &Bs[2048 + w * 512]);
    __syncthreads();
    short8 af[4], bf[4];
#pragma unroll
    for (int i = 0; i < 4; i++) af[i] = *(const short8*)&As[(wr * 64 + i * 16 + lr) * 32 + lg * 8];
#pragma unroll
    for (int i = 0; i < 4; i++) bf[i] = *(const short8*)&Bs[(wc * 64 + i * 16 + lr) * 32 + lg * 8];
#pragma unroll
    for (int i = 0; i < 4; i++)
#pragma unroll
      for (int j = 0; j < 4; j++)
        acc[i][j] = __builtin_amdgcn_mfma_f32_16x16x32_bf16(af[i], bf[j], acc[i][j], 0, 0, 0);
    __syncthreads();
  }
  const int rbase = byy * 128 + wr * 64;
  const int cbase = bxx * 128 + wc * 64;
#pragma unroll
  for (int i = 0; i < 4; i++)
#pragma unroll
    for (int j = 0; j < 4; j++) {
      const int c = cbase + j * 16 + lr;
      const float bz = bias[c];
#pragma unroll
      for (int v = 0; v < 4; v++) {
        const int r = rbase + i * 16 + lg * 4 + v;
        float val = acc[i][j][v] + bz;
        if (RES) val += res[(size_t)r * N + c];
        if (GELU) val = 0.5f * val * (1.0f + erff(val * 0.70710678118654752f));
        if (OUT_BF16) Cb[(size_t)r * N + c] = f2bf(val);
        else          Cf[(size_t)r * N + c] = val;
      }
    }
}

// ---------------- fused attention (v4: swapped QK^T -> per-lane q-row softmax) ----
// qkv bf16 [8192][2304]; vT bf16 [8*768][1024]; o bf16 [8192][768]
// grid (16 qtiles, 12 heads, 8 batch), 256 threads (4 waves, 16 q-rows each)
// LDS tiles [row][64] bf16, byte-XOR swizzle: byte_in_row ^= (row&7)<<4.
// Swapped QK^T: sf[n] = mfma(K_frag, Q_frag) -> lane holds S[q=lr][k=n*16+lg*4+v]
// => row max/sum = 16 local ops + 2 shfl_xor; P-writes = 4x ds_write_b64.
__global__ __launch_bounds__(256) void attn(const unsigned short* __restrict__ qkv,
                                            const unsigned short* __restrict__ vT,
                                            unsigned short* __restrict__ o) {
  const int qt = blockIdx.x, h = blockIdx.y, b = blockIdx.z;
  const int t = threadIdx.x, w = t >> 6, l = t & 63;
  const int lr = l & 15, lg = l >> 4;
  const int ld = 3 * DIMC;
  __shared__ __align__(16) unsigned short Ks[64 * 64];
  __shared__ __align__(16) unsigned short Vt[64 * 64];
  __shared__ __align__(16) unsigned short Ps[4][16 * 64];

  const unsigned short* qb = qkv + (size_t)(b * SEQ + qt * 64 + w * 16) * ld + h * HDIM;
  short8 qf0 = *(const short8*)(qb + (size_t)lr * ld + lg * 8);        // Q rows q=lr (B-operand)
  short8 qf1 = *(const short8*)(qb + (size_t)lr * ld + 32 + lg * 8);

  const unsigned short* vrow = vT + (size_t)(b * DIMC + h * HDIM + (t >> 2)) * SEQ;

  float m_run = -1e30f, l_run = 0.f;   // stats for q = w*16 + lr (replicated over lg)
  f32x4 oacc[4];                       // O[q=lg*4+v][d=dn*16+lr]
#pragma unroll
  for (int i = 0; i < 4; i++) oacc[i] = (f32x4){0.f, 0.f, 0.f, 0.f};

  for (int kt = 0; kt < 16; ++kt) {
    const unsigned short* kb = qkv + (size_t)(b * SEQ + kt * 64) * ld + DIMC + h * HDIM;
    {
      const int r = t >> 2, c4 = (t & 3) * 16;
      const int sw = (r & 7) << 4;
      short8 kv0 = *(const short8*)(kb + (size_t)r * ld + c4);
      short8 kv1 = *(const short8*)(kb + (size_t)r * ld + c4 + 8);
      char* ksb = (char*)Ks + r * 128;
      *(short8*)(ksb + ((c4 * 2) ^ sw))      = kv0;
      *(short8*)(ksb + ((c4 * 2 + 16) ^ sw)) = kv1;
      short8 tv0 = *(const short8*)(vrow + kt * 64 + c4);
      short8 tv1 = *(const short8*)(vrow + kt * 64 + c4 + 8);
      char* vsb = (char*)Vt + r * 128;
      *(short8*)(vsb + ((c4 * 2) ^ sw))      = tv0;
      *(short8*)(vsb + ((c4 * 2 + 16) ^ sw)) = tv1;
    }
    __syncthreads();

    // ---- swapped QK^T: sf[n][v] = S[q=lr][k=n*16+lg*4+v] ----
    f32x4 sf[4];
#pragma unroll
    for (int n = 0; n < 4; n++) sf[n] = (f32x4){0.f, 0.f, 0.f, 0.f};
#pragma unroll
    for (int kc = 0; kc < 2; kc++) {
      short8 q = kc ? qf1 : qf0;
#pragma unroll
      for (int n = 0; n < 4; n++) {
        const int row = n * 16 + lr;
        short8 kf = *(const short8*)((const char*)Ks + row * 128 +
                                     (((kc * 32 + lg * 8) * 2) ^ ((row & 7) << 4)));
        sf[n] = __builtin_amdgcn_mfma_f32_16x16x32_bf16(kf, q, sf[n], 0, 0, 0);
      }
    }

    // ---- online softmax, q = lr local ----
    float pv[4][4];
    float tmax = -1e30f;
#pragma unroll
    for (int n = 0; n < 4; n++)
#pragma unroll
      for (int v = 0; v < 4; v++) {
        float s = sf[n][v] * 0.125f;
        s = fminf(fmaxf(s, -50.f), 50.f);
        pv[n][v] = s;
        tmax = fmaxf(tmax, s);
      }
    tmax = fmaxf(tmax, __shfl_xor(tmax, 16));
    tmax = fmaxf(tmax, __shfl_xor(tmax, 32));
    const float mn = fmaxf(m_run, tmax);
    const float alpha = __expf(m_run - mn);
    m_run = mn;
    l_run *= alpha;
    float psum = 0.f;
    char* psw = (char*)&Ps[w][0] + lr * 128;
    const int psx = (lr & 7) << 4;
#pragma unroll
    for (int n = 0; n < 4; n++) {
      us4 pk;
#pragma unroll
      for (int v = 0; v < 4; v++) {
        float e = __expf(pv[n][v] - mn);
        psum += e;
        pk[v] = f2bf(e);
      }
      *(us4*)(psw + ((n * 32 + lg * 8) ^ psx)) = pk;   // P[q=lr][k=n*16+lg*4 ..+3]
    }
    psum += __shfl_xor(psum, 16);
    psum += __shfl_xor(psum, 32);
    l_run += psum;

    // rescale oacc rows q=lg*4+v with that q's alpha (broadcast from lane lr==q)
#pragma unroll
    for (int v = 0; v < 4; v++) {
      const float av = __shfl(alpha, lg * 4 + v);
#pragma unroll
      for (int dn = 0; dn < 4; dn++) oacc[dn][v] *= av;
    }

    // drain wave-local Ps writes before reading them (no block barrier needed)
    asm volatile("s_waitcnt lgkmcnt(0)" ::: "memory");
    __builtin_amdgcn_sched_barrier(0);

    // ---- PV: A = P[q=lr][k-frag], B = Vt[d=dn*16+lr][k-frag] (swizzled reads) ----
#pragma unroll
    for (int kc = 0; kc < 2; kc++) {
      short8 pf = *(const short8*)((const char*)&Ps[w][0] + lr * 128 +
                                   (((kc * 32 + lg * 8) * 2) ^ ((lr & 7) << 4)));
#pragma unroll
      for (int dn = 0; dn < 4; dn++) {
        const int row = dn * 16 + lr;
        short8 vf = *(const short8*)((const char*)Vt + row * 128 +
                                     (((kc * 32 + lg * 8) * 2) ^ ((row & 7) << 4)));
        oacc[dn] = __builtin_amdgcn_mfma_f32_16x16x32_bf16(pf, vf, oacc[dn], 0, 0, 0);
      }
    }
    __syncthreads();
  }

  unsigned short* ob = o + (size_t)(b * SEQ + qt * 64 + w * 16) * DIMC + h * HDIM;
#pragma unroll
  for (int v = 0; v < 4; v++) {
    const float lv = __shfl(l_run, lg * 4 + v);
    const float inv = 1.0f / lv;
#pragma unroll
    for (int dn = 0; dn < 4; dn++)
      ob[(size_t)(lg * 4 + v) * DIMC + dn * 16 + lr] = f2bf(oacc[dn][v] * inv);
  }
}

extern "C" void kernel_launch(void* const* d_in, const int* in_sizes, int n_in,
                              void* d_out, int out_size, void* d_ws, size_t ws_size,
                              hipStream_t stream) {
  const float* x      = (const float*)d_in[0];
  const float* ln1_g  = (const float*)d_in[1];
  const float* ln1_b  = (const float*)d_in[2];
  const float* w_qkv  = (const float*)d_in[3];
  const float* b_qkv  = (const float*)d_in[4];
  const float* w_proj = (const float*)d_in[5];
  const float* b_proj = (const float*)d_in[6];
  const float* ln2_g  = (const float*)d_in[7];
  const float* ln2_b  = (const float*)d_in[8];
  const float* w_fc1  = (const float*)d_in[9];
  const float* b_fc1  = (const float*)d_in[10];
  const float* w_fc2  = (const float*)d_in[11];
  const float* b_fc2  = (const float*)d_in[12];
  float* out = (float*)d_out;

  char* p = (char*)d_ws;
  unsigned short* wqkvT  = (unsigned short*)p; p += (size_t)2304 * 768 * 2;
  unsigned short* wprojT = (unsigned short*)p; p += (size_t)768 * 768 * 2;
  unsigned short* wfc1T  = (unsigned short*)p; p += (size_t)3072 * 768 * 2;
  unsigned short* wfc2T  = (unsigned short*)p; p += (size_t)768 * 3072 * 2;
  unsigned short* h1     = (unsigned short*)p; p += (size_t)NTOK * 768 * 2;
  float*          x1     = (float*)p;          p += (size_t)NTOK * 768 * 4;
  unsigned short* qkv    = (unsigned short*)p; p += (size_t)NTOK * 2304 * 2;
  unsigned short* ob     = (unsigned short*)p; p += (size_t)NTOK * 768 * 2;
  unsigned short* g      = qkv;            // alias: qkv region, dead by FC1
  unsigned short* vT     = (unsigned short*)x1;  // alias: x1 dead until proj GEMM; vT dead after attn

  dim3 tb(32, 8);
  wtrans<<<dim3(2304 / 32, 768 / 32), tb, 0, stream>>>(w_qkv, wqkvT, 768, 2304);
  wtrans<<<dim3(768 / 32, 768 / 32), tb, 0, stream>>>(w_proj, wprojT, 768, 768);
  wtrans<<<dim3(3072 / 32, 768 / 32), tb, 0, stream>>>(w_fc1, wfc1T, 768, 3072);
  wtrans<<<dim3(768 / 32, 3072 / 32), tb, 0, stream>>>(w_fc2, wfc2T, 3072, 768);

  ln_768<<<NTOK, 256, 0, stream>>>(x, ln1_g, ln1_b, h1);
  gemm_bt<0, 0, 1><<<dim3(18, 64), 256, 0, stream>>>(h1, wqkvT, b_qkv, nullptr, nullptr, qkv,
                                                     NTOK, 2304, 768);
  vtrans<<<dim3(24, 32, 8), tb, 0, stream>>>(qkv, vT);
  attn<<<dim3(16, 12, 8), 256, 0, stream>>>(qkv, vT, ob);
  gemm_bt<0, 1, 0><<<dim3(6, 64), 256, 0, stream>>>(ob, wprojT, b_proj, x, x1, nullptr,
                                                    NTOK, 768, 768);
  ln_768<<<NTOK, 256, 0, stream>>>(x1, ln2_g, ln2_b, h1);
  gemm_bt<1, 0, 1><<<dim3(24, 64), 256, 0, stream>>>(h1, wfc1T, b_fc1, nullptr, nullptr, g,
                                                     NTOK, 3072, 768);
  gemm_bt<0, 1, 0><<<dim3(6, 64), 256, 0, stream>>>(g, wfc2T, b_fc2, x1, out, nullptr,
                                                    NTOK, 768, 3072);
}

// Round 7
// 314.299 us; speedup vs baseline: 1.2502x; 1.0192x over previous
//
#include <hip/hip_runtime.h>
#include <hip/hip_bf16.h>

typedef __attribute__((ext_vector_type(8))) short short8;
typedef __attribute__((ext_vector_type(4))) float f32x4;
typedef __attribute__((ext_vector_type(4))) unsigned short us4;

#define DIMC 768
#define HIDDENC 3072
#define NTOK 8192
#define SEQ 1024
#define NHEAD 12
#define HDIM 64

__device__ inline unsigned short f2bf(float f) {
  union { float f; unsigned u; } x; x.f = f;
  unsigned r = (x.u + 0x7FFFu + ((x.u >> 16) & 1u)) >> 16;
  return (unsigned short)r;
}

__device__ inline void gload_lds16(const void* g, void* lds) {
  __builtin_amdgcn_global_load_lds((const __attribute__((address_space(1))) unsigned*)g,
                                   (__attribute__((address_space(3))) unsigned*)lds, 16, 0, 0);
}

// ---------------- weight transpose + fp32->bf16 ----------------
// W: [K][N] f32  ->  Wt: [N][K] bf16
__global__ void wtrans(const float* __restrict__ W, unsigned short* __restrict__ Wt,
                       int K, int N) {
  __shared__ float tile[32][33];
  const int bx = blockIdx.x * 32;  // N
  const int by = blockIdx.y * 32;  // K
  const int tx = threadIdx.x, ty = threadIdx.y;
#pragma unroll
  for (int i = 0; i < 32; i += 8) tile[ty + i][tx] = W[(size_t)(by + ty + i) * N + bx + tx];
  __syncthreads();
#pragma unroll
  for (int i = 0; i < 32; i += 8)
    Wt[(size_t)(bx + ty + i) * K + by + tx] = f2bf(tile[tx][ty + i]);
}

// ---------------- V transpose: qkv V-part -> vT[b*768 + (h*64+d)][n] ----------------
__global__ void vtrans(const unsigned short* __restrict__ qkv, unsigned short* __restrict__ vT) {
  __shared__ unsigned short tile[32][33];
  const int bc = blockIdx.x * 32;  // c in [0,768)
  const int bn = blockIdx.y * 32;  // n in [0,1024)
  const int b = blockIdx.z;
  const int tx = threadIdx.x, ty = threadIdx.y;
#pragma unroll
  for (int i = 0; i < 32; i += 8)
    tile[ty + i][tx] = qkv[(size_t)(b * SEQ + bn + ty + i) * (3 * DIMC) + 2 * DIMC + bc + tx];
  __syncthreads();
#pragma unroll
  for (int i = 0; i < 32; i += 8)
    vT[(size_t)(b * DIMC + bc + ty + i) * SEQ + bn + tx] = tile[tx][ty + i];
}

// ---------------- LayerNorm over 768, f32 in -> bf16 out ----------------
__global__ __launch_bounds__(256) void ln_768(const float* __restrict__ x,
                                              const float* __restrict__ g,
                                              const float* __restrict__ b,
                                              unsigned short* __restrict__ out) {
  const int row = blockIdx.x;
  const int t = threadIdx.x;
  const float* xr = x + (size_t)row * DIMC;
  float v0 = xr[t], v1 = xr[t + 256], v2 = xr[t + 512];
  float s = v0 + v1 + v2;
  float ss = v0 * v0 + v1 * v1 + v2 * v2;
#pragma unroll
  for (int m = 1; m < 64; m <<= 1) { s += __shfl_xor(s, m); ss += __shfl_xor(ss, m); }
  __shared__ float red[8];
  const int w = t >> 6, l = t & 63;
  if (l == 0) { red[w] = s; red[4 + w] = ss; }
  __syncthreads();
  s = red[0] + red[1] + red[2] + red[3];
  ss = red[4] + red[5] + red[6] + red[7];
  const float mu = s * (1.0f / 768.0f);
  const float var = ss * (1.0f / 768.0f) - mu * mu;
  const float rstd = rsqrtf(var + 1e-5f);
  out[(size_t)row * DIMC + t]       = f2bf((v0 - mu) * rstd * g[t]       + b[t]);
  out[(size_t)row * DIMC + t + 256] = f2bf((v1 - mu) * rstd * g[t + 256] + b[t + 256]);
  out[(size_t)row * DIMC + t + 512] = f2bf((v2 - mu) * rstd * g[t + 512] + b[t + 512]);
}

// ---------------- GEMM v2: 2-phase double-buffered LDS ----------------
// C[M][N] = A[M][K] @ Bt[N][K]^T + bias (+res) (+gelu). 128x128 tile, BK=32,
// 4 waves (2x2). Next tile's global_load_lds issued BEFORE current compute;
// single __syncthreads per K-step (its implicit vmcnt(0)+lgkmcnt(0) drain sits
// after the MFMA phase = the minimum 2-phase pipeline). nt = K/32 must be even.
// XCD-aware block swizzle (grid sizes all %8==0).
template <int GELU, int RES, int OUT_BF16>
__global__ __launch_bounds__(256) void gemm_bt(const unsigned short* __restrict__ A,
                                               const unsigned short* __restrict__ Bt,
                                               const float* __restrict__ bias,
                                               const float* __restrict__ res,
                                               float* __restrict__ Cf,
                                               unsigned short* __restrict__ Cb,
                                               int M, int N, int K) {
  __shared__ __align__(16) unsigned short As[2][128 * 32];
  __shared__ __align__(16) unsigned short Bs[2][128 * 32];
  const int gx = gridDim.x;
  const int nwg = gx * gridDim.y;
  const int orig = blockIdx.y * gx + blockIdx.x;
  const int cpx = nwg >> 3;                       // nwg % 8 == 0
  const int wg = (orig & 7) * cpx + (orig >> 3);
  const int bxx = wg % gx, byy = wg / gx;
  const int t = threadIdx.x;
  const int w = t >> 6, l = t & 63;
  const int lr = l & 15, lg = l >> 4;
  const int wr = w >> 1, wc = w & 1;
  const unsigned short* Ag = A + (size_t)byy * 128 * K;
  const unsigned short* Bg = Bt + (size_t)bxx * 128 * K;
  const int c1 = t, c2 = t + 256;
  const size_t a1 = (size_t)(c1 >> 2) * K + (size_t)(c1 & 3) * 8;
  const size_t a2 = (size_t)(c2 >> 2) * K + (size_t)(c2 & 3) * 8;
  f32x4 acc[4][4] = {};

  auto stage4 = [&](int buf, int k0) {
    gload_lds16(Ag + a1 + k0, &As[buf][w * 512]);
    gload_lds16(Ag + a2 + k0, &As[buf][2048 + w * 512]);
    gload_lds16(Bg + a1 + k0, &Bs[buf][w * 512]);
    gload_lds16(Bg + a2 + k0, &Bs[buf][2048 + w * 512]);
  };
  auto compute = [&](int buf) {
    short8 af[4], bf[4];
#pragma unroll
    for (int i = 0; i < 4; i++)
      af[i] = *(const short8*)&As[buf][(wr * 64 + i * 16 + lr) * 32 + lg * 8];
#pragma unroll
    for (int i = 0; i < 4; i++)
      bf[i] = *(const short8*)&Bs[buf][(wc * 64 + i * 16 + lr) * 32 + lg * 8];
#pragma unroll
    for (int i = 0; i < 4; i++)
#pragma unroll
      for (int j = 0; j < 4; j++)
        acc[i][j] = __builtin_amdgcn_mfma_f32_16x16x32_bf16(af[i], bf[j], acc[i][j], 0, 0, 0);
  };

  const int nt = K >> 5;  // even for all our K (768->24, 3072->96)
  stage4(0, 0);
  __syncthreads();
  for (int tt = 0; tt < nt; tt += 2) {
    stage4(1, (tt + 1) << 5);   // prefetch tile tt+1 (always valid: tt+1 <= nt-1)
    compute(0);
    __syncthreads();            // drains prefetch (overlapped with compute) + read fence
    if (tt + 2 < nt) stage4(0, (tt + 2) << 5);
    compute(1);
    __syncthreads();
  }

  const int rbase = byy * 128 + wr * 64;
  const int cbase = bxx * 128 + wc * 64;
#pragma unroll
  for (int i = 0; i < 4; i++)
#pragma unroll
    for (int j = 0; j < 4; j++) {
      const int c = cbase + j * 16 + lr;
      const float bz = bias[c];
#pragma unroll
      for (int v = 0; v < 4; v++) {
        const int r = rbase + i * 16 + lg * 4 + v;
        float val = acc[i][j][v] + bz;
        if (RES) val += res[(size_t)r * N + c];
        if (GELU) {
          // gelu(u) ~= u * sigmoid(1.595769f*(u + 0.044715f*u^3)); inf-safe.
          const float u = val;
          const float c2u = u * (1.5957691216f + 0.0713548162f * u * u);
          val = u - u * __builtin_amdgcn_rcpf(__expf(c2u) + 1.0f);
        }
        if (OUT_BF16) Cb[(size_t)r * N + c] = f2bf(val);
        else          Cf[(size_t)r * N + c] = val;
      }
    }
}

// ---------------- fused attention (v5: v4 + T14 async K/V reg-prefetch) ----
// qkv bf16 [8192][2304]; vT bf16 [8*768][1024]; o bf16 [8192][768]
// grid (16 qtiles, 12 heads, 8 batch), 256 threads (4 waves, 16 q-rows each)
// LDS tiles [row][64] bf16, byte-XOR swizzle: byte_in_row ^= (row&7)<<4.
// Raw s_barrier (not __syncthreads) so the prefetch global loads stay in
// flight across barriers; their only hardware wait is the compiler's vmcnt
// before next iteration's ds_write.
__global__ __launch_bounds__(256) void attn(const unsigned short* __restrict__ qkv,
                                            const unsigned short* __restrict__ vT,
                                            unsigned short* __restrict__ o) {
  const int qt = blockIdx.x, h = blockIdx.y, b = blockIdx.z;
  const int t = threadIdx.x, w = t >> 6, l = t & 63;
  const int lr = l & 15, lg = l >> 4;
  const int ld = 3 * DIMC;
  __shared__ __align__(16) unsigned short Ks[64 * 64];
  __shared__ __align__(16) unsigned short Vt[64 * 64];
  __shared__ __align__(16) unsigned short Ps[4][16 * 64];

  const unsigned short* qb = qkv + (size_t)(b * SEQ + qt * 64 + w * 16) * ld + h * HDIM;
  short8 qf0 = *(const short8*)(qb + (size_t)lr * ld + lg * 8);        // Q rows q=lr (B-operand)
  short8 qf1 = *(const short8*)(qb + (size_t)lr * ld + 32 + lg * 8);

  const int r = t >> 2, c4 = (t & 3) * 16;
  const int sw = (r & 7) << 4;
  const unsigned short* kb_base = qkv + (size_t)(b * SEQ) * ld + DIMC + h * HDIM + (size_t)r * ld;
  const unsigned short* vrow = vT + (size_t)(b * DIMC + h * HDIM + r) * SEQ;

  // staging regs for current tile (kt=0)
  short8 ck0 = *(const short8*)(kb_base + c4);
  short8 ck1 = *(const short8*)(kb_base + c4 + 8);
  short8 cv0 = *(const short8*)(vrow + c4);
  short8 cv1 = *(const short8*)(vrow + c4 + 8);

  float m_run = -1e30f, l_run = 0.f;   // stats for q = w*16 + lr (replicated over lg)
  f32x4 oacc[4];                       // O[q=lg*4+v][d=dn*16+lr]
#pragma unroll
  for (int i = 0; i < 4; i++) oacc[i] = (f32x4){0.f, 0.f, 0.f, 0.f};

  for (int kt = 0; kt < 16; ++kt) {
    // ---- write current K/V tile to LDS (swizzled) ----
    {
      char* ksb = (char*)Ks + r * 128;
      *(short8*)(ksb + ((c4 * 2) ^ sw))      = ck0;
      *(short8*)(ksb + ((c4 * 2 + 16) ^ sw)) = ck1;
      char* vsb = (char*)Vt + r * 128;
      *(short8*)(vsb + ((c4 * 2) ^ sw))      = cv0;
      *(short8*)(vsb + ((c4 * 2 + 16) ^ sw)) = cv1;
    }
    // ---- prefetch next tile into regs (clamped; last iter wasted but valid) ----
    const int nk = (kt + 1) & 15;
    short8 nk0 = *(const short8*)(kb_base + (size_t)nk * 64 * ld + c4);
    short8 nk1 = *(const short8*)(kb_base + (size_t)nk * 64 * ld + c4 + 8);
    short8 nv0 = *(const short8*)(vrow + nk * 64 + c4);
    short8 nv1 = *(const short8*)(vrow + nk * 64 + c4 + 8);

    asm volatile("s_waitcnt lgkmcnt(0)" ::: "memory");  // K/V ds_writes visible
    __builtin_amdgcn_s_barrier();
    __builtin_amdgcn_sched_barrier(0);

    // ---- swapped QK^T: sf[n][v] = S[q=lr][k=n*16+lg*4+v] ----
    f32x4 sf[4];
#pragma unroll
    for (int n = 0; n < 4; n++) sf[n] = (f32x4){0.f, 0.f, 0.f, 0.f};
#pragma unroll
    for (int kc = 0; kc < 2; kc++) {
      short8 q = kc ? qf1 : qf0;
#pragma unroll
      for (int n = 0; n < 4; n++) {
        const int row = n * 16 + lr;
        short8 kf = *(const short8*)((const char*)Ks + row * 128 +
                                     (((kc * 32 + lg * 8) * 2) ^ ((row & 7) << 4)));
        sf[n] = __builtin_amdgcn_mfma_f32_16x16x32_bf16(kf, q, sf[n], 0, 0, 0);
      }
    }

    // ---- online softmax, q = lr local ----
    float pv[4][4];
    float tmax = -1e30f;
#pragma unroll
    for (int n = 0; n < 4; n++)
#pragma unroll
      for (int v = 0; v < 4; v++) {
        float s = sf[n][v] * 0.125f;
        s = fminf(fmaxf(s, -50.f), 50.f);
        pv[n][v] = s;
        tmax = fmaxf(tmax, s);
      }
    tmax = fmaxf(tmax, __shfl_xor(tmax, 16));
    tmax = fmaxf(tmax, __shfl_xor(tmax, 32));
    const float mn = fmaxf(m_run, tmax);
    const float alpha = __expf(m_run - mn);
    m_run = mn;
    l_run *= alpha;
    float psum = 0.f;
    char* psw = (char*)&Ps[w][0] + lr * 128;
    const int psx = (lr & 7) << 4;
#pragma unroll
    for (int n = 0; n < 4; n++) {
      us4 pk;
#pragma unroll
      for (int v = 0; v < 4; v++) {
        float e = __expf(pv[n][v] - mn);
        psum += e;
        pk[v] = f2bf(e);
      }
      *(us4*)(psw + ((n * 32 + lg * 8) ^ psx)) = pk;   // P[q=lr][k=n*16+lg*4 ..+3]
    }
    psum += __shfl_xor(psum, 16);
    psum += __shfl_xor(psum, 32);
    l_run += psum;

    // rescale oacc rows q=lg*4+v with that q's alpha (broadcast from lane lr==q)
#pragma unroll
    for (int v = 0; v < 4; v++) {
      const float av = __shfl(alpha, lg * 4 + v);
#pragma unroll
      for (int dn = 0; dn < 4; dn++) oacc[dn][v] *= av;
    }

    // drain wave-local Ps writes before reading them (no block barrier needed)
    asm volatile("s_waitcnt lgkmcnt(0)" ::: "memory");
    __builtin_amdgcn_sched_barrier(0);

    // ---- PV: A = P[q=lr][k-frag], B = Vt[d=dn*16+lr][k-frag] (swizzled reads) ----
#pragma unroll
    for (int kc = 0; kc < 2; kc++) {
      short8 pf = *(const short8*)((const char*)&Ps[w][0] + lr * 128 +
                                   (((kc * 32 + lg * 8) * 2) ^ ((lr & 7) << 4)));
#pragma unroll
      for (int dn = 0; dn < 4; dn++) {
        const int row = dn * 16 + lr;
        short8 vf = *(const short8*)((const char*)Vt + row * 128 +
                                     (((kc * 32 + lg * 8) * 2) ^ ((row & 7) << 4)));
        oacc[dn] = __builtin_amdgcn_mfma_f32_16x16x32_bf16(pf, vf, oacc[dn], 0, 0, 0);
      }
    }
    __builtin_amdgcn_sched_barrier(0);
    __builtin_amdgcn_s_barrier();   // all waves done reading Ks/Vt before next overwrite
    ck0 = nk0; ck1 = nk1; cv0 = nv0; cv1 = nv1;
  }

  unsigned short* ob = o + (size_t)(b * SEQ + qt * 64 + w * 16) * DIMC + h * HDIM;
#pragma unroll
  for (int v = 0; v < 4; v++) {
    const float lv = __shfl(l_run, lg * 4 + v);
    const float inv = 1.0f / lv;
#pragma unroll
    for (int dn = 0; dn < 4; dn++)
      ob[(size_t)(lg * 4 + v) * DIMC + dn * 16 + lr] = f2bf(oacc[dn][v] * inv);
  }
}

extern "C" void kernel_launch(void* const* d_in, const int* in_sizes, int n_in,
                              void* d_out, int out_size, void* d_ws, size_t ws_size,
                              hipStream_t stream) {
  const float* x      = (const float*)d_in[0];
  const float* ln1_g  = (const float*)d_in[1];
  const float* ln1_b  = (const float*)d_in[2];
  const float* w_qkv  = (const float*)d_in[3];
  const float* b_qkv  = (const float*)d_in[4];
  const float* w_proj = (const float*)d_in[5];
  const float* b_proj = (const float*)d_in[6];
  const float* ln2_g  = (const float*)d_in[7];
  const float* ln2_b  = (const float*)d_in[8];
  const float* w_fc1  = (const float*)d_in[9];
  const float* b_fc1  = (const float*)d_in[10];
  const float* w_fc2  = (const float*)d_in[11];
  const float* b_fc2  = (const float*)d_in[12];
  float* out = (float*)d_out;

  char* p = (char*)d_ws;
  unsigned short* wqkvT  = (unsigned short*)p; p += (size_t)2304 * 768 * 2;
  unsigned short* wprojT = (unsigned short*)p; p += (size_t)768 * 768 * 2;
  unsigned short* wfc1T  = (unsigned short*)p; p += (size_t)3072 * 768 * 2;
  unsigned short* wfc2T  = (unsigned short*)p; p += (size_t)768 * 3072 * 2;
  unsigned short* h1     = (unsigned short*)p; p += (size_t)NTOK * 768 * 2;
  float*          x1     = (float*)p;          p += (size_t)NTOK * 768 * 4;
  unsigned short* qkv    = (unsigned short*)p; p += (size_t)NTOK * 2304 * 2;
  unsigned short* ob     = (unsigned short*)p; p += (size_t)NTOK * 768 * 2;
  unsigned short* g      = qkv;            // alias: qkv region, dead by FC1
  unsigned short* vT     = (unsigned short*)x1;  // alias: x1 dead until proj GEMM; vT dead after attn

  dim3 tb(32, 8);
  wtrans<<<dim3(2304 / 32, 768 / 32), tb, 0, stream>>>(w_qkv, wqkvT, 768, 2304);
  wtrans<<<dim3(768 / 32, 768 / 32), tb, 0, stream>>>(w_proj, wprojT, 768, 768);
  wtrans<<<dim3(3072 / 32, 768 / 32), tb, 0, stream>>>(w_fc1, wfc1T, 768, 3072);
  wtrans<<<dim3(768 / 32, 3072 / 32), tb, 0, stream>>>(w_fc2, wfc2T, 3072, 768);

  ln_768<<<NTOK, 256, 0, stream>>>(x, ln1_g, ln1_b, h1);
  gemm_bt<0, 0, 1><<<dim3(18, 64), 256, 0, stream>>>(h1, wqkvT, b_qkv, nullptr, nullptr, qkv,
                                                     NTOK, 2304, 768);
  vtrans<<<dim3(24, 32, 8), tb, 0, stream>>>(qkv, vT);
  attn<<<dim3(16, 12, 8), 256, 0, stream>>>(qkv, vT, ob);
  gemm_bt<0, 1, 0><<<dim3(6, 64), 256, 0, stream>>>(ob, wprojT, b_proj, x, x1, nullptr,
                                                    NTOK, 768, 768);
  ln_768<<<NTOK, 256, 0, stream>>>(x1, ln2_g, ln2_b, h1);
  gemm_bt<1, 0, 1><<<dim3(24, 64), 256, 0, stream>>>(h1, wfc1T, b_fc1, nullptr, nullptr, g,
                                                     NTOK, 3072, 768);
  gemm_bt<0, 1, 0><<<dim3(6, 64), 256, 0, stream>>>(g, wfc2T, b_fc2, x1, out, nullptr,
                                                    NTOK, 768, 3072);
}